// Round 6
// baseline (602.456 us; speedup 1.0000x reference)
//
#include <hip/hip_runtime.h>

// SHAPE = (16, 128, 4096, 3): rows = 2048, row_len = 12288 floats = 3072 float4.
// R6: single fused kernel (last-block pattern) to remove the second launch +
// serial final kernel (~5-6 us of the 94). Work decomposition as R5 (uniform
// 48KB-read blocks):
//   blocks 0..8191     : euclid QUARTER-row (row r = b>>2, quarter q = b&3)
//   blocks 8192..10239 : var FULL row
// Every block publishes partials to ws, __threadfence(), atomicAdd ticket;
// the LAST block re-reads all partials in FIXED order -> deterministic result.
// Ticket counter is reset to 0 every call via hipMemsetAsync (capture-legal).
#define NROW    2048
#define ROW_V4  3072
#define QRT_V4  768
#define NT      256
#define NEB     8192
#define NVB     2048
#define TOTB    (NEB + NVB)

__global__ __launch_bounds__(NT) void fused(
    const float* __restrict__ outp,
    const float* __restrict__ targp,
    const float* __restrict__ g1p,
    const float* __restrict__ g2p,
    const float* __restrict__ gvp,
    const float* __restrict__ gt0p,
    const float* __restrict__ legp,
    const float* __restrict__ ldynp,
    float4* __restrict__ eucbuf,       // [8192] {so,s1,s2,0} per quarter-row
    float*  __restrict__ varbuf,       // [2048] per-row var sums
    unsigned int* __restrict__ ticket, // reset to 0 each call
    float* __restrict__ resp)
{
    __shared__ float red[4][5];
    const int bid  = blockIdx.x;
    const int tid  = threadIdx.x;
    const int wid  = tid >> 6;
    const int lane = tid & 63;

    if (bid < NEB) {
        const int r = bid >> 2;
        const int q = bid & 3;
        const size_t base = (size_t)r * ROW_V4 + (size_t)q * QRT_V4;
        const float4* __restrict__ t4 = (const float4*)targp + base;
        const float4* __restrict__ o4 = (const float4*)outp  + base;
        const float4* __restrict__ a4 = (const float4*)g1p   + base;
        const float4* __restrict__ b4 = (const float4*)g2p   + base;

        float so = 0.f, s1 = 0.f, s2 = 0.f;
        #pragma unroll
        for (int k = 0; k < 3; ++k) {
            const int i = tid + k * NT;
            const float4 t = t4[i];
            const float4 o = o4[i];
            const float4 a = a4[i];
            const float4 b = b4[i];
            float d;
            d = o.x - t.x; so = fmaf(d, d, so);
            d = o.y - t.y; so = fmaf(d, d, so);
            d = o.z - t.z; so = fmaf(d, d, so);
            d = o.w - t.w; so = fmaf(d, d, so);
            d = a.x - t.x; s1 = fmaf(d, d, s1);
            d = a.y - t.y; s1 = fmaf(d, d, s1);
            d = a.z - t.z; s1 = fmaf(d, d, s1);
            d = a.w - t.w; s1 = fmaf(d, d, s1);
            d = b.x - t.x; s2 = fmaf(d, d, s2);
            d = b.y - t.y; s2 = fmaf(d, d, s2);
            d = b.z - t.z; s2 = fmaf(d, d, s2);
            d = b.w - t.w; s2 = fmaf(d, d, s2);
        }
        #pragma unroll
        for (int off = 32; off; off >>= 1) {
            so += __shfl_down(so, off);
            s1 += __shfl_down(s1, off);
            s2 += __shfl_down(s2, off);
        }
        if (lane == 0) { red[wid][0] = so; red[wid][1] = s1; red[wid][2] = s2; }
        __syncthreads();
        if (tid == 0) {
            float r0 = 0.f, r1 = 0.f, r2 = 0.f;
            #pragma unroll
            for (int w = 0; w < 4; ++w) { r0 += red[w][0]; r1 += red[w][1]; r2 += red[w][2]; }
            eucbuf[bid] = make_float4(r0, r1, r2, 0.f);
        }
    } else {
        const int rv = bid - NEB;
        const size_t base = (size_t)rv * ROW_V4;
        const float4* __restrict__ v4 = (const float4*)gvp + base;
        float sb = 0.f;
        #pragma unroll
        for (int k = 0; k < 12; ++k) {
            const float4 v = v4[tid + k * NT];
            sb += fmaf(v.x, v.x * 0.125f, -__logf(v.x));
            sb += fmaf(v.y, v.y * 0.125f, -__logf(v.y));
            sb += fmaf(v.z, v.z * 0.125f, -__logf(v.z));
            sb += fmaf(v.w, v.w * 0.125f, -__logf(v.w));
        }
        #pragma unroll
        for (int off = 32; off; off >>= 1) sb += __shfl_down(sb, off);
        if (lane == 0) red[wid][0] = sb;
        __syncthreads();
        if (tid == 0)
            varbuf[rv] = red[0][0] + red[1][0] + red[2][0] + red[3][0];
    }

    // ---- last-block final reduction (deterministic: fixed read order) ----
    __syncthreads();                 // all lanes' partial published via tid==0 store
    __shared__ bool amlast;
    if (tid == 0) {
        __threadfence();             // make this block's partial visible device-wide
        const unsigned int old = atomicAdd(ticket, 1u);
        amlast = (old == TOTB - 1);
    }
    __syncthreads();
    if (!amlast) return;
    __threadfence();                 // acquire: see all other blocks' partials

    float A0 = 0.f, A1 = 0.f, A2 = 0.f, K = 0.f, SB = 0.f;
    #pragma unroll
    for (int h = 0; h < 8; ++h) {
        const int r = tid + h * NT;
        float so = 0.f, s1 = 0.f, s2 = 0.f;
        #pragma unroll
        for (int q = 0; q < 4; ++q) {
            const float4 e = eucbuf[4 * r + q];
            so += e.x; s1 += e.y; s2 += e.z;
        }
        A0 += sqrtf(so);
        A1 += sqrtf(s1);
        A2 += sqrtf(s2);
        K  += fmaf(0.125f, so, fmaf(0.025f, s1, 0.025f * s2));
        SB += varbuf[r];
    }
    #pragma unroll
    for (int off = 32; off; off >>= 1) {
        A0 += __shfl_down(A0, off);
        A1 += __shfl_down(A1, off);
        A2 += __shfl_down(A2, off);
        K  += __shfl_down(K,  off);
        SB += __shfl_down(SB, off);
    }
    __syncthreads();                 // red[] reuse
    if (lane == 0) {
        red[wid][0] = A0; red[wid][1] = A1; red[wid][2] = A2;
        red[wid][3] = K;  red[wid][4] = SB;
    }
    __syncthreads();
    if (tid == 0) {
        float r0 = 0.f, r1 = 0.f, r2 = 0.f, r3 = 0.f, rb = 0.f;
        #pragma unroll
        for (int w = 0; w < 4; ++w) {
            r0 += red[w][0]; r1 += red[w][1]; r2 += red[w][2];
            r3 += red[w][3]; rb += red[w][4];
        }
        const float Eo = r0 * (1.f / 128.f);
        const float E1 = r1 * (1.f / 128.f);
        const float E2 = r2 * (1.f / 128.f);
        const float kl = 1.4f * (rb + 25165824.f * (0.69314718056f - 0.5f)) + r3;

        const float l_dyn    = ldynp[0];
        const float leg_term = 0.01f * 0.2f * l_dyn * legp[0];
        const float outloss  = Eo + leg_term;
        const float gt_loss  = 0.1f * E1 + 0.2f * E2;
        const float reg      = gt0p[0] * 0.01f * l_dyn;

        resp[0] = outloss + gt_loss + reg + kl / (1.2f * (Eo + gt_loss));
    }
}

extern "C" void kernel_launch(void* const* d_in, const int* in_sizes, int n_in,
                              void* d_out, int out_size, void* d_ws, size_t ws_size,
                              hipStream_t stream) {
    const float* outp  = (const float*)d_in[0];
    const float* targp = (const float*)d_in[1];
    const float* gt0p  = (const float*)d_in[2];
    const float* g1p   = (const float*)d_in[3];
    const float* g2p   = (const float*)d_in[4];
    const float* gvp   = (const float*)d_in[5];
    const float* legp  = (const float*)d_in[6];
    const float* ldynp = (const float*)d_in[7];

    // ws layout: [ticket u32 + pad 16B][eucbuf 8192*float4][varbuf 2048*float]
    unsigned int* ticket = (unsigned int*)d_ws;
    float4* eucbuf = (float4*)((char*)d_ws + 16);
    float*  varbuf = (float*)(eucbuf + NEB);
    float*  resp   = (float*)d_out;

    hipMemsetAsync(ticket, 0, sizeof(unsigned int), stream);
    fused<<<TOTB, NT, 0, stream>>>(outp, targp, g1p, g2p, gvp,
                                   gt0p, legp, ldynp,
                                   eucbuf, varbuf, ticket, resp);
}

// Round 7
// 95.166 us; speedup vs baseline: 6.3306x; 6.3306x over previous
//
#include <hip/hip_runtime.h>

// SHAPE = (16, 128, 4096, 3): rows = 2048, row_len = 12288 floats = 3072 float4.
// FINAL (revert to R5): two-kernel structure. R6's fused last-block variant
// regressed 6.4x — per-block device-scope fences on CDNA4 (non-coherent
// per-XCD L2) trigger full L2 writebacks and serialize the TCC.
// Work decomposition: uniform 48KB-read blocks,
//   blocks 0..8191     : euclid QUARTER-row (row r = b>>2, quarter q = b&3),
//                        4 streams x 12KB, partial {so,s1,s2} -> eucbuf[b]
//   blocks 8192..10239 : var FULL row (1 stream x 48KB) -> varbuf[b-8192]
// final_kernel re-forms per-row sums from the 4 quarters BEFORE sqrt.
// Delivered BW ~5.7 TB/s = ~93% of the measured 10 B/cyc/CU streaming ceiling.
#define NROW    2048
#define ROW_V4  3072
#define QRT_V4  768            // float4 per quarter-row
#define NT      256
#define NEB     8192           // euclid blocks
#define NVB     2048           // var blocks

__global__ __launch_bounds__(NT) void pass1(
    const float* __restrict__ outp,
    const float* __restrict__ targp,
    const float* __restrict__ g1p,
    const float* __restrict__ g2p,
    const float* __restrict__ gvp,
    float4* __restrict__ eucbuf,     // [8192] {so, s1, s2, 0} per quarter-row
    float*  __restrict__ varbuf)     // [2048] per-row sums of (-log v + v^2/8)
{
    __shared__ float red[4][3];
    const int bid  = blockIdx.x;
    const int tid  = threadIdx.x;
    const int wid  = tid >> 6;
    const int lane = tid & 63;

    if (bid < NEB) {
        const int r = bid >> 2;
        const int q = bid & 3;
        const size_t base = (size_t)r * ROW_V4 + (size_t)q * QRT_V4;
        const float4* __restrict__ t4 = (const float4*)targp + base;
        const float4* __restrict__ o4 = (const float4*)outp  + base;
        const float4* __restrict__ a4 = (const float4*)g1p   + base;
        const float4* __restrict__ b4 = (const float4*)g2p   + base;

        float so = 0.f, s1 = 0.f, s2 = 0.f;
        #pragma unroll
        for (int k = 0; k < 3; ++k) {
            const int i = tid + k * NT;
            const float4 t = t4[i];
            const float4 o = o4[i];
            const float4 a = a4[i];
            const float4 b = b4[i];
            float d;
            d = o.x - t.x; so = fmaf(d, d, so);
            d = o.y - t.y; so = fmaf(d, d, so);
            d = o.z - t.z; so = fmaf(d, d, so);
            d = o.w - t.w; so = fmaf(d, d, so);
            d = a.x - t.x; s1 = fmaf(d, d, s1);
            d = a.y - t.y; s1 = fmaf(d, d, s1);
            d = a.z - t.z; s1 = fmaf(d, d, s1);
            d = a.w - t.w; s1 = fmaf(d, d, s1);
            d = b.x - t.x; s2 = fmaf(d, d, s2);
            d = b.y - t.y; s2 = fmaf(d, d, s2);
            d = b.z - t.z; s2 = fmaf(d, d, s2);
            d = b.w - t.w; s2 = fmaf(d, d, s2);
        }
        #pragma unroll
        for (int off = 32; off; off >>= 1) {
            so += __shfl_down(so, off);
            s1 += __shfl_down(s1, off);
            s2 += __shfl_down(s2, off);
        }
        if (lane == 0) { red[wid][0] = so; red[wid][1] = s1; red[wid][2] = s2; }
        __syncthreads();
        if (tid == 0) {
            float r0 = 0.f, r1 = 0.f, r2 = 0.f;
            #pragma unroll
            for (int w = 0; w < 4; ++w) { r0 += red[w][0]; r1 += red[w][1]; r2 += red[w][2]; }
            eucbuf[bid] = make_float4(r0, r1, r2, 0.f);
        }
    } else {
        const int rv = bid - NEB;
        const size_t base = (size_t)rv * ROW_V4;
        const float4* __restrict__ v4 = (const float4*)gvp + base;
        float sb = 0.f;
        #pragma unroll
        for (int k = 0; k < 12; ++k) {
            const float4 v = v4[tid + k * NT];
            sb += fmaf(v.x, v.x * 0.125f, -__logf(v.x));
            sb += fmaf(v.y, v.y * 0.125f, -__logf(v.y));
            sb += fmaf(v.z, v.z * 0.125f, -__logf(v.z));
            sb += fmaf(v.w, v.w * 0.125f, -__logf(v.w));
        }
        #pragma unroll
        for (int off = 32; off; off >>= 1) sb += __shfl_down(sb, off);
        if (lane == 0) red[wid][0] = sb;
        __syncthreads();
        if (tid == 0)
            varbuf[rv] = red[0][0] + red[1][0] + red[2][0] + red[3][0];
    }
}

// Single block, 1024 threads. Re-form per-row sums (4 quarters), sqrt, and the
// final scalar formula. Fully deterministic (fixed summation order per thread,
// fixed tree across waves).
__global__ __launch_bounds__(1024) void final_kernel(
    const float4* __restrict__ eucbuf,
    const float*  __restrict__ varbuf,
    const float*  __restrict__ gt0p,
    const float*  __restrict__ legp,
    const float*  __restrict__ ldynp,
    float* __restrict__ resp)
{
    const int tid = threadIdx.x;
    float A0 = 0.f, A1 = 0.f, A2 = 0.f, K = 0.f, SB = 0.f;

    // 2048 rows over 1024 threads: rows tid and tid+1024
    #pragma unroll
    for (int h = 0; h < 2; ++h) {
        const int r = tid + h * 1024;
        float so = 0.f, s1 = 0.f, s2 = 0.f;
        #pragma unroll
        for (int q = 0; q < 4; ++q) {
            const float4 e = eucbuf[4 * r + q];
            so += e.x; s1 += e.y; s2 += e.z;
        }
        A0 += sqrtf(so);
        A1 += sqrtf(s1);
        A2 += sqrtf(s2);
        K  += fmaf(0.125f, so, fmaf(0.025f, s1, 0.025f * s2));
        SB += varbuf[r];
    }

    #pragma unroll
    for (int off = 32; off; off >>= 1) {
        A0 += __shfl_down(A0, off);
        A1 += __shfl_down(A1, off);
        A2 += __shfl_down(A2, off);
        K  += __shfl_down(K,  off);
        SB += __shfl_down(SB, off);
    }
    __shared__ float red[16][5];
    const int wid  = tid >> 6;
    const int lane = tid & 63;
    if (lane == 0) {
        red[wid][0] = A0; red[wid][1] = A1; red[wid][2] = A2;
        red[wid][3] = K;  red[wid][4] = SB;
    }
    __syncthreads();
    if (tid == 0) {
        float r0 = 0.f, r1 = 0.f, r2 = 0.f, r3 = 0.f, rb = 0.f;
        #pragma unroll
        for (int w = 0; w < 16; ++w) {
            r0 += red[w][0]; r1 += red[w][1]; r2 += red[w][2];
            r3 += red[w][3]; rb += red[w][4];
        }
        const float Eo = r0 * (1.f / 128.f);
        const float E1 = r1 * (1.f / 128.f);
        const float E2 = r2 * (1.f / 128.f);
        // kl = 1.4*(SB + N*(ln2 - 0.5)) + (SO + 0.2*S1 + 0.2*S2)/8
        const float kl = 1.4f * (rb + 25165824.f * (0.69314718056f - 0.5f)) + r3;

        const float l_dyn    = ldynp[0];
        const float leg_term = 0.01f * 0.2f * l_dyn * legp[0];
        const float outloss  = Eo + leg_term;
        const float gt_loss  = 0.1f * E1 + 0.2f * E2;
        const float reg      = gt0p[0] * 0.01f * l_dyn;

        resp[0] = outloss + gt_loss + reg + kl / (1.2f * (Eo + gt_loss));
    }
}

extern "C" void kernel_launch(void* const* d_in, const int* in_sizes, int n_in,
                              void* d_out, int out_size, void* d_ws, size_t ws_size,
                              hipStream_t stream) {
    const float* outp  = (const float*)d_in[0];
    const float* targp = (const float*)d_in[1];
    const float* gt0p  = (const float*)d_in[2];
    const float* g1p   = (const float*)d_in[3];
    const float* g2p   = (const float*)d_in[4];
    const float* gvp   = (const float*)d_in[5];
    const float* legp  = (const float*)d_in[6];
    const float* ldynp = (const float*)d_in[7];

    float4* eucbuf = (float4*)d_ws;                 // 8192 * 16 B = 128 KiB
    float*  varbuf = (float*)(eucbuf + NEB);        // 2048 * 4 B  =   8 KiB
    float*  resp   = (float*)d_out;

    pass1<<<NEB + NVB, NT, 0, stream>>>(outp, targp, g1p, g2p, gvp, eucbuf, varbuf);
    final_kernel<<<1, 1024, 0, stream>>>(eucbuf, varbuf, gt0p, legp, ldynp, resp);
}